// Round 1
// baseline (144.290 us; speedup 1.0000x reference)
//
#include <hip/hip_runtime.h>
#include <hip/hip_bf16.h>
#include <stdint.h>

#define B_   4
#define N_   10000
#define K_   16
#define D_   256
#define OUT_ 256
#define M_   (B_ * N_)          // 40000
#define CW   32                 // bf16 cols per y2 chunk (64-B rows)
#define NCH  8                  // chunks (one per XCD)
#define CHUNK_ELEMS ((size_t)N_ * B_ * CW)   // 1,280,000 ushorts = 2.56 MB

typedef __attribute__((ext_vector_type(8))) short          short8;    // MFMA frag
typedef __attribute__((ext_vector_type(8))) unsigned short ushort8;
typedef __attribute__((ext_vector_type(4))) float          f32x4;
typedef __attribute__((ext_vector_type(4))) unsigned short ushort4_t;

__device__ inline unsigned short f2bf(float f) {
    __hip_bfloat16 h = __float2bfloat16(f);
    return *reinterpret_cast<unsigned short*>(&h);
}
__device__ inline float bf2f(unsigned short u) {
    unsigned int v = ((unsigned int)u) << 16;
    return __builtin_bit_cast(float, v);
}

// ---------------------------------------------------------------------------
// wprep: W (256 x 512 f32, row o = [W1_o | W2_o]) -> Wb (512 x 256 bf16)
//   Wb[o][k]     = W[o][k]       (y1 = x @ W1^T)
//   Wb[256+o][k] = W[o][256+k]   (y2 = x @ W2^T)
// 128 blocks, no dependency on x -> negligible critical-path cost.
// ---------------------------------------------------------------------------
__global__ __launch_bounds__(256) void wprep(const float* __restrict__ W,
                                             unsigned short* __restrict__ Wb) {
    const int g  = blockIdx.x * 256 + threadIdx.x;   // 0..32767
    const int op = g >> 6;                           // 0..511
    const int k0 = (g & 63) * 4;
    const float* src = (op < OUT_) ? (W + (size_t)op * 512 + k0)
                                   : (W + (size_t)(op - OUT_) * 512 + 256 + k0);
    const float4 v = *(const float4*)src;
    ushort4_t s;
    s.x = f2bf(v.x); s.y = f2bf(v.y); s.z = f2bf(v.z); s.w = f2bf(v.w);
    *(ushort4_t*)(Wb + (size_t)op * 256 + k0) = s;
}

// ---------------------------------------------------------------------------
// gemm_fused: y[m, o'] = x[m, :] . Wb[o', :]   (M=40000, K=256, N'=512)
//   A (x fp32) is reg-staged + converted to bf16 in-kernel (prep pass gone).
//   B via global_load_lds(16B) from bf16 Wb (proven pattern).
//   half = blockIdx&1 selects output col-half:
//     half 0 -> y1 fp32, m-row-major (self term, full precision kept)
//     half 1 -> y2 bf16, chunk-major [8][ (n*4+b) ][32] (gather-ready)
// 1250 blocks x 256 thr, tile 64x256, BK=32, 8 k-steps, ~20 KB LDS.
// ---------------------------------------------------------------------------
__global__ __launch_bounds__(256) void gemm_fused(const float* __restrict__ x,
                                                  const unsigned short* __restrict__ Wb,
                                                  float* __restrict__ y1,
                                                  unsigned short* __restrict__ y2c) {
    __shared__ unsigned short As[64 * 32];    //  4 KB
    __shared__ unsigned short Bs[256 * 32];   // 16 KB

    const int tid    = threadIdx.x;
    const int w      = tid >> 6;
    const int lane   = tid & 63;
    const int q      = lane >> 4;
    const int r16    = lane & 15;
    const int half   = blockIdx.x & 1;
    const int tile_m = (blockIdx.x >> 1) * 64;

    const int crow = lane >> 2;        // row within a 16-row B chunk
    const int kofs = (lane & 3) * 8;   // ushort offset within BK=32

    // A staging coords: 64 rows x 32 k fp32 = 2048 f32 / 256 thr = 8 each
    const int arow  = tid >> 2;        // 0..63
    const int acol8 = (tid & 3) * 8;   // 0,8,16,24
    const float* xrow = x + (size_t)(tile_m + arow) * D_ + acol8;

    // B source base: row = half*256 + (w*4+t)*16 + crow
    const unsigned short* bsrc =
        Wb + ((size_t)(half * OUT_ + w * 64 + crow)) * D_ + kofs;

    f32x4 acc[4][4] = {};

    // prefetch first A sub-tile into regs
    float4 va0 = *(const float4*)(xrow);
    float4 va1 = *(const float4*)(xrow + 4);

    for (int kk = 0; kk < D_; kk += 32) {
        // issue B global->LDS (stays in flight until the barrier drain)
#pragma unroll
        for (int t = 0; t < 4; ++t) {
            __builtin_amdgcn_global_load_lds(
                (const __attribute__((address_space(1))) void*)(bsrc + (size_t)t * 16 * D_ + kk),
                (__attribute__((address_space(3))) void*)(Bs + (w * 4 + t) * 512),
                16, 0, 0);
        }
        // convert current A regs -> LDS
        ushort8 s;
        s[0] = f2bf(va0.x); s[1] = f2bf(va0.y); s[2] = f2bf(va0.z); s[3] = f2bf(va0.w);
        s[4] = f2bf(va1.x); s[5] = f2bf(va1.y); s[6] = f2bf(va1.z); s[7] = f2bf(va1.w);
        *(ushort8*)(As + arow * 32 + acol8) = s;
        // prefetch next A sub-tile (latency overlaps the barrier drain + MFMA)
        if (kk + 32 < D_) {
            va0 = *(const float4*)(xrow + kk + 32);
            va1 = *(const float4*)(xrow + kk + 36);
        }
        __syncthreads();

        short8 a[4], bf[4];
#pragma unroll
        for (int i = 0; i < 4; ++i)
            a[i] = *(const short8*)(As + (i * 16 + r16) * 32 + q * 8);
#pragma unroll
        for (int j = 0; j < 4; ++j)
            bf[j] = *(const short8*)(Bs + (w * 64 + j * 16 + r16) * 32 + q * 8);

#pragma unroll
        for (int i = 0; i < 4; ++i)
#pragma unroll
            for (int j = 0; j < 4; ++j)
                acc[i][j] = __builtin_amdgcn_mfma_f32_16x16x32_bf16(a[i], bf[j], acc[i][j], 0, 0, 0);

        __syncthreads();
    }

    if (half == 0) {
        // y1 fp32, m-row-major (coalesced 16-lane runs)
#pragma unroll
        for (int i = 0; i < 4; ++i) {
#pragma unroll
            for (int reg = 0; reg < 4; ++reg) {
                const int m = tile_m + i * 16 + q * 4 + reg;
                float* row = y1 + (size_t)m * OUT_ + w * 64;
#pragma unroll
                for (int j = 0; j < 4; ++j)
                    row[j * 16 + r16] = acc[i][j][reg];
            }
        }
    } else {
        // y2 bf16, chunk-major: row (n*4+b), chunk = col>>5 (matches gather)
#pragma unroll
        for (int i = 0; i < 4; ++i) {
#pragma unroll
            for (int reg = 0; reg < 4; ++reg) {
                const int m = tile_m + i * 16 + q * 4 + reg;
                const int b = (m >= N_) + (m >= 2 * N_) + (m >= 3 * N_);
                const int n = m - b * N_;
                unsigned short* rbase = y2c + (size_t)(n * B_ + b) * CW;
#pragma unroll
                for (int j = 0; j < 4; ++j) {
                    const int o2 = w * 64 + j * 16 + r16;    // col within y2's 256
                    rbase[(size_t)(o2 >> 5) * CHUNK_ELEMS + (o2 & 31)] =
                        f2bf(acc[i][j][reg]);
                }
            }
        }
    }
}

// ---------------------------------------------------------------------------
// gather_out: out[b,n,o] = relu( y1[b,n,o] + (1/cnt) sum_k y2[b,neigh[n,k],o]
//                                + bias[o] )
// Same proven L2-chunked gather as before (chunk c = blockIdx&7 -> XCD,
// 2.56-MB chunk resident in that XCD's L2; 16 independent 16-B gathers per
// thread), now fused with the streaming y1 + bias + ReLU epilogue.
// ---------------------------------------------------------------------------
__global__ __launch_bounds__(256) void gather_out(const unsigned short* __restrict__ y2c,
                                                  const float* __restrict__ y1,
                                                  const int*   __restrict__ neigh,
                                                  const float* __restrict__ bias,
                                                  float* __restrict__ out) {
    const int c   = blockIdx.x & 7;
    const int g   = blockIdx.x >> 3;
    const int n0  = g * 16;
    const int tid = threadIdx.x;

    __shared__ int   idx_s[16 * K_];   // 256 ints
    __shared__ float inv_s[16];

    idx_s[tid] = neigh[n0 * K_ + tid];
    __syncthreads();
    if (tid < 16) {
        int cnt = 0;
#pragma unroll
        for (int k = 0; k < K_; ++k) cnt += idx_s[tid * K_ + k] >= 0 ? 1 : 0;
        inv_s[tid] = 1.0f / (float)(cnt > 1 ? cnt : 1);
    }
    __syncthreads();

    const int q  = tid & 3;          // 8-col group within the 32-col chunk
    const int tl = tid >> 2;         // task 0..63
    const int ns = tl >> 2;          // node_sub 0..15
    const int b  = tl & 3;           // batch

    const unsigned short* ycc = y2c + (size_t)c * CHUNK_ELEMS;

    int jj[K_];
#pragma unroll
    for (int k = 0; k < K_; ++k) jj[k] = idx_s[ns * K_ + k];

    // 16 independent 16-B gather loads from the L2-resident chunk
    ushort8 vv[K_];
#pragma unroll
    for (int k = 0; k < K_; ++k) {
        const int jc = jj[k] >= 0 ? jj[k] : 0;
        vv[k] = *(const ushort8*)(ycc + ((size_t)jc * B_ + b) * CW + q * 8);
    }

    // streaming self term + bias (issued while gathers are in flight)
    const size_t mo = (size_t)(b * N_ + n0 + ns) * OUT_ + c * CW + q * 8;
    const f32x4 s0 = *(const f32x4*)(y1 + mo);
    const f32x4 s1 = *(const f32x4*)(y1 + mo + 4);
    const f32x4 b0 = *(const f32x4*)(bias + c * CW + q * 8);
    const f32x4 b1 = *(const f32x4*)(bias + c * CW + q * 8 + 4);

    float acc[8] = {0.f, 0.f, 0.f, 0.f, 0.f, 0.f, 0.f, 0.f};
#pragma unroll
    for (int k = 0; k < K_; ++k) {
        const float m = jj[k] >= 0 ? 1.f : 0.f;
#pragma unroll
        for (int e = 0; e < 8; ++e) acc[e] += bf2f(vv[k][e]) * m;
    }
    const float inv = inv_s[ns];

    f32x4 o0, o1;
#pragma unroll
    for (int e = 0; e < 4; ++e) {
        float v0 = acc[e] * inv + s0[e] + b0[e];
        float v1 = acc[e + 4] * inv + s1[e] + b1[e];
        o0[e] = v0 > 0.f ? v0 : 0.f;
        o1[e] = v1 > 0.f ? v1 : 0.f;
    }
    // out is never re-read: nontemporal to avoid evicting the gather chunk
    __builtin_nontemporal_store(o0, (f32x4*)(out + mo));
    __builtin_nontemporal_store(o1, (f32x4*)(out + mo + 4));
}

// ---------------------------------------------------------------------------
extern "C" void kernel_launch(void* const* d_in, const int* in_sizes, int n_in,
                              void* d_out, int out_size, void* d_ws, size_t ws_size,
                              hipStream_t stream) {
    const float* x     = (const float*)d_in[0];   // (4, 10000, 256) fp32
    const int*   neigh = (const int*)d_in[1];     // (10000, 16) int32
    const float* W     = (const float*)d_in[2];   // (256, 512) fp32
    const float* bias  = (const float*)d_in[3];   // (256,) fp32
    float*       out   = (float*)d_out;           // (4, 10000, 256) fp32

    unsigned short* Wb  = (unsigned short*)d_ws;          // 512*256 bf16 = 0.26 MB
    float*          y1  = (float*)(Wb + 512 * D_);        // 40000*256 f32 = 40.96 MB
    unsigned short* y2c = (unsigned short*)(y1 + (size_t)M_ * OUT_);  // 8 x 2.56 MB

    wprep<<<128, 256, 0, stream>>>(W, Wb);
    gemm_fused<<<(M_ / 64) * 2, 256, 0, stream>>>(x, Wb, y1, y2c);
    gather_out<<<(N_ / 16) * NCH, 256, 0, stream>>>(y2c, y1, neigh, bias, out);
}